// Round 5
// baseline (778.872 us; speedup 1.0000x reference)
//
#include <hip/hip_runtime.h>

// EvolveGCN — only the GRU weight evolution is sequential; graph conv runs
// once on feats[7]. Round 5:
//   phase1: LDS-tiled gate transpose (coalesced) ∥ degree histogram
//   phase2: gru (2 cols/block) ∥ 4-wave shfl scan ∥ rdeg
//   phase3: build_csr ∥ gemm_z (4x16 register tile) ∥ W2m = W2@mlp_w1
//   phase4: gather128 + fused (H1@W2m)·rdegO -> Ys   (H1 never leaves LDS)
//   phase5: gather64 + fused MLP head -> out

#define HM1 127

static constexpr float RRELU_SLOPE = (1.0f / 8.0f + 1.0f / 3.0f) * 0.5f;

__device__ __forceinline__ float sigmoidf_(float x) {
    return 1.0f / (1.0f + expf(-x));
}

// ---------------------------------------------------------------------------
// phase1: blocks [0,32): LDS-tiled transpose of gate matrices into AT;
//         blocks [32,32+nbE): degree histogram.
//   AT[m][k][i] layout, m: 0..3 cell1 {z:W+U, r:W+U, W2, U2}, 4..7 cell2.
// ---------------------------------------------------------------------------
__global__ __launch_bounds__(256) void phase1(
    const int* __restrict__ src, const int* __restrict__ dst,
    int* __restrict__ degO, int* __restrict__ degI, int E,
    const float* __restrict__ g1W, const float* __restrict__ g1U,
    const float* __restrict__ g2W, const float* __restrict__ g2U,
    float* __restrict__ AT)
{
    int bid = blockIdx.x;
    if (bid < 32) {
        __shared__ float tile[64][65];
        int m     = bid >> 2;
        int itile = bid & 1;          // source row-block = AT col-block
        int ktile = (bid >> 1) & 1;   // source col-block = AT row-block
        const float* W = (m < 4) ? g1W : g2W;
        const float* U = (m < 4) ? g1U : g2U;
        int which = m & 3;
        const float* P;
        const float* Q2 = nullptr;
        if (which == 0)      { P = W;         Q2 = U; }
        else if (which == 1) { P = W + 16384; Q2 = U + 16384; }
        else if (which == 2) { P = W + 32768; }
        else                 { P = U + 32768; }
        int c  = threadIdx.x & 63;
        int r4 = threadIdx.x >> 6;    // 0..3
        #pragma unroll
        for (int rr = 0; rr < 16; ++rr) {
            int row = itile * 64 + rr * 4 + r4;
            int col = ktile * 64 + c;
            float v = P[row * 128 + col];
            if (Q2) v += Q2[row * 128 + col];
            tile[rr * 4 + r4][c] = v;
        }
        __syncthreads();
        float* ATm = AT + m * 16384;
        #pragma unroll
        for (int rr = 0; rr < 16; ++rr) {
            int krow = ktile * 64 + rr * 4 + r4;
            ATm[krow * 128 + itile * 64 + c] = tile[c][rr * 4 + r4];
        }
    } else {
        int e = (bid - 32) * 256 + threadIdx.x;
        if (e < E) {
            atomicAdd(&degO[src[e]], 1);
            atomicAdd(&degI[dst[e]], 1);
        }
    }
}

// ---------------------------------------------------------------------------
// phase2: blocks [0,128): gru (2 cols/block, 8 steps);
//         block 128: 4-wave two-pass coalesced shfl-scan degI -> row_ptr;
//         blocks [129,129+nbN): rdeg.
// ---------------------------------------------------------------------------
__global__ __launch_bounds__(256) void phase2(
    const float* __restrict__ W1_0, const float* __restrict__ W2_0,
    const float* __restrict__ AT,
    const float* __restrict__ g1b, const float* __restrict__ g2b,
    float* __restrict__ W1f, float* __restrict__ W2f,
    const int* __restrict__ degO, const int* __restrict__ degI,
    float* __restrict__ rdegO, float* __restrict__ rdegI,
    int* __restrict__ row_ptr, int N)
{
    __shared__ float smem[512];
    int bid = blockIdx.x;
    if (bid < 128) {
        const int half = threadIdx.x >> 7;
        const int i = threadIdx.x & 127;
        int c = bid * 2 + half;               // 0..255
        if (c > 254) c = 254;                 // dup col 254; same-value write
        const int cell = (c >= 128) ? 1 : 0;
        const int cc = cell ? (c - 128) : c;

        const float* A  = AT + cell * 4 * 16384;
        const float* A0 = A;
        const float* A1 = A + 16384;
        const float* B0 = A + 32768;
        const float* B1 = A + 49152;
        const float* gb = cell ? g2b : g1b;
        const int   ldb = cell ? HM1 : 128;
        const float* W0 = cell ? W2_0 : W1_0;
        const int   ldw = cell ? HM1 : 128;

        float* w  = smem + half * 128;
        float* rw = smem + 256 + half * 128;

        const float zb = gb[i * ldb + cc];
        const float rb = gb[128 * ldb + i * ldb + cc];
        const float hb = gb[2 * 128 * ldb + i * ldb + cc];
        float wi = W0[i * ldw + cc];
        w[i] = wi;
        __syncthreads();

        for (int s = 0; s < 8; ++s) {
            float zacc = zb, racc = rb, tacc = hb;
            #pragma unroll 4
            for (int k = 0; k < 128; ++k) {
                float wk = w[k];
                zacc += A0[k * 128 + i] * wk;
                racc += A1[k * 128 + i] * wk;
                tacc += B0[k * 128 + i] * wk;
            }
            float r = sigmoidf_(racc);
            rw[i] = r * wi;
            __syncthreads();
            #pragma unroll 4
            for (int k = 0; k < 128; ++k)
                tacc += B1[k * 128 + i] * rw[k];
            float z = sigmoidf_(zacc);
            float t = tanhf(tacc);
            float nwi = (1.0f - z) * wi + z * t;
            __syncthreads();
            wi = nwi;
            w[i] = nwi;
            __syncthreads();
        }
        float* Wf = cell ? W2f : W1f;
        Wf[i * 128 + cc] = wi;        // ld=128 (W2f padded)
    } else if (bid == 128) {
        __shared__ int qsum[4];
        const int t = threadIdx.x, w = t >> 6, l = t & 63;
        const int Q = (((N + 3) >> 2) + 63) & ~63;
        const int qlo = w * Q;
        const int qhi = min(qlo + Q, N);
        // pass 1: per-wave quarter totals (coalesced)
        int s = 0;
        for (int i2 = qlo + l; i2 < qhi; i2 += 64) s += degI[i2];
        #pragma unroll
        for (int d = 32; d; d >>= 1) s += __shfl_xor(s, d);
        if (l == 0) qsum[w] = s;
        __syncthreads();
        int base = 0;
        for (int q = 0; q < w; ++q) base += qsum[q];
        if (t == 0) row_ptr[N] = qsum[0] + qsum[1] + qsum[2] + qsum[3];
        // pass 2: wave shfl-scan per 64-chunk (coalesced)
        int carry = base;
        for (int b = qlo; b < qhi; b += 64) {
            int i2 = b + l;
            int v = (i2 < qhi) ? degI[i2] : 0;
            int incl = v;
            #pragma unroll
            for (int d = 1; d < 64; d <<= 1) {
                int nbr = __shfl_up(incl, d);
                if (l >= d) incl += nbr;
            }
            if (i2 < qhi) row_ptr[i2] = carry + incl - v;
            carry += __shfl(incl, 63);
        }
    } else {
        int n = (bid - 129) * 256 + threadIdx.x;
        if (n < N) {
            rdegO[n] = rsqrtf(fmaxf((float)degO[n], 1.0f));
            rdegI[n] = rsqrtf(fmaxf((float)degI[n], 1.0f));
        }
    }
}

// ---------------------------------------------------------------------------
// phase3: blocks [0,nbE): build_csr; [nbE,nbE+ngz): gemm_z; last 32: W2m.
// gemm_z: Zs = rdegO ⊙ (x7 @ W1f), register-tiled 4 rows x 16 cols/thread.
// ---------------------------------------------------------------------------
__global__ __launch_bounds__(256) void phase3(
    const int* __restrict__ src, const int* __restrict__ dst,
    const int* __restrict__ row_ptr, int* __restrict__ cursor,
    int* __restrict__ srcs, int E, int nbE,
    const float* __restrict__ x7, const float* __restrict__ W1f,
    const float* __restrict__ rdegO, float* __restrict__ Zs, int N, int ngz,
    const float* __restrict__ W2f, const float* __restrict__ mw1,
    float* __restrict__ W2m)
{
    int bid = blockIdx.x;
    if (bid < nbE) {
        int e = bid * 256 + threadIdx.x;
        if (e < E) {
            int d = dst[e];
            int pos = row_ptr[d] + atomicAdd(&cursor[d], 1);
            srcs[pos] = src[e];
        }
    } else if (bid < nbE + ngz) {
        int b  = bid - nbE;
        int cb = b & 7;               // 16-col block
        int rg = b >> 3;              // 1024-row group
        int c0 = cb * 16;
        int r0 = rg * 1024 + threadIdx.x;

        float acc[4][16];
        #pragma unroll
        for (int r = 0; r < 4; ++r)
            #pragma unroll
            for (int j = 0; j < 16; ++j) acc[r][j] = 0.0f;

        const float4* x0p = (const float4*)(x7 + (size_t)min(r0,       N - 1) * 128);
        const float4* x1p = (const float4*)(x7 + (size_t)min(r0 + 256, N - 1) * 128);
        const float4* x2p = (const float4*)(x7 + (size_t)min(r0 + 512, N - 1) * 128);
        const float4* x3p = (const float4*)(x7 + (size_t)min(r0 + 768, N - 1) * 128);

        for (int k4 = 0; k4 < 32; ++k4) {
            float4 v0 = x0p[k4], v1 = x1p[k4], v2 = x2p[k4], v3 = x3p[k4];
            const float* wb = W1f + (k4 * 4) * 128 + c0;
#define ZSTEP(KK, S0, S1, S2, S3)                                           \
            {                                                               \
                const float* wr_ = wb + (KK) * 128;                         \
                float4 wa = *(const float4*)(wr_ + 0);                      \
                float4 wq = *(const float4*)(wr_ + 4);                      \
                float4 wc = *(const float4*)(wr_ + 8);                      \
                float4 wd = *(const float4*)(wr_ + 12);                     \
                float w16[16] = {wa.x, wa.y, wa.z, wa.w, wq.x, wq.y, wq.z, wq.w, \
                                 wc.x, wc.y, wc.z, wc.w, wd.x, wd.y, wd.z, wd.w}; \
                float ss[4] = {S0, S1, S2, S3};                             \
                _Pragma("unroll")                                           \
                for (int r = 0; r < 4; ++r) {                               \
                    _Pragma("unroll")                                       \
                    for (int j = 0; j < 16; ++j) acc[r][j] += ss[r] * w16[j]; \
                }                                                           \
            }
            ZSTEP(0, v0.x, v1.x, v2.x, v3.x)
            ZSTEP(1, v0.y, v1.y, v2.y, v3.y)
            ZSTEP(2, v0.z, v1.z, v2.z, v3.z)
            ZSTEP(3, v0.w, v1.w, v2.w, v3.w)
#undef ZSTEP
        }

        #pragma unroll
        for (int r = 0; r < 4; ++r) {
            int row = r0 + r * 256;
            if (row < N) {
                float ro = rdegO[row];
                float* zr = Zs + (size_t)row * 128 + c0;
                #pragma unroll
                for (int j = 0; j < 16; j += 4) {
                    float4 o;
                    o.x = acc[r][j] * ro;     o.y = acc[r][j + 1] * ro;
                    o.z = acc[r][j + 2] * ro; o.w = acc[r][j + 3] * ro;
                    *(float4*)(zr + j) = o;
                }
            }
        }
    } else {
        int idx = (bid - nbE - ngz) * 256 + threadIdx.x;  // < 8192
        int i = idx >> 6, j = idx & 63;
        float acc = 0.0f;
        for (int k = 0; k < HM1; ++k)
            acc += W2f[i * 128 + k] * mw1[k * 64 + j];
        W2m[idx] = acc;
    }
}

// ---------------------------------------------------------------------------
// phase4: block = 4 nodes. Wave w gathers node n: H1[n]=rrelu(rdegI·ΣZs[s]),
// staged in LDS; then 256 threads compute Ys[n,:] = rdegO[n]·(H1[n]@W2m).
// ---------------------------------------------------------------------------
__global__ __launch_bounds__(256) void phase4(
    const float* __restrict__ Zs, const int* __restrict__ srcs,
    const int* __restrict__ row_ptr, const float* __restrict__ rdegI,
    const float* __restrict__ rdegO, const float* __restrict__ W2m,
    float* __restrict__ Ys, int N)
{
    __shared__ float h[4][128];
    const int t = threadIdx.x, w = t >> 6, l = t & 63;
    const int n = blockIdx.x * 4 + w;
    int lo = 0, hi = 0;
    float ri = 0.0f;
    if (n < N) { lo = row_ptr[n]; hi = row_ptr[n + 1]; ri = rdegI[n]; }
    float ax = 0.0f, ay = 0.0f;
    for (int base = lo; base < hi; base += 64) {
        int cnt = min(hi - base, 64);
        int idx = (l < cnt) ? srcs[base + l] : 0;
        int j = 0;
        for (; j + 8 <= cnt; j += 8) {
            int s0 = __shfl(idx, j + 0), s1 = __shfl(idx, j + 1);
            int s2 = __shfl(idx, j + 2), s3 = __shfl(idx, j + 3);
            int s4 = __shfl(idx, j + 4), s5 = __shfl(idx, j + 5);
            int s6 = __shfl(idx, j + 6), s7 = __shfl(idx, j + 7);
            float2 v0 = *(const float2*)(Zs + (size_t)s0 * 128 + l * 2);
            float2 v1 = *(const float2*)(Zs + (size_t)s1 * 128 + l * 2);
            float2 v2 = *(const float2*)(Zs + (size_t)s2 * 128 + l * 2);
            float2 v3 = *(const float2*)(Zs + (size_t)s3 * 128 + l * 2);
            float2 v4 = *(const float2*)(Zs + (size_t)s4 * 128 + l * 2);
            float2 v5 = *(const float2*)(Zs + (size_t)s5 * 128 + l * 2);
            float2 v6 = *(const float2*)(Zs + (size_t)s6 * 128 + l * 2);
            float2 v7 = *(const float2*)(Zs + (size_t)s7 * 128 + l * 2);
            ax += v0.x + v1.x + v2.x + v3.x + v4.x + v5.x + v6.x + v7.x;
            ay += v0.y + v1.y + v2.y + v3.y + v4.y + v5.y + v6.y + v7.y;
        }
        for (; j < cnt; ++j) {
            int s0 = __shfl(idx, j);
            float2 v0 = *(const float2*)(Zs + (size_t)s0 * 128 + l * 2);
            ax += v0.x;
            ay += v0.y;
        }
    }
    ax *= ri; ay *= ri;
    ax = ax >= 0.0f ? ax : RRELU_SLOPE * ax;
    ay = ay >= 0.0f ? ay : RRELU_SLOPE * ay;
    *(float2*)&h[w][2 * l] = make_float2(ax, ay);
    __syncthreads();

    // Ys[n2,:] = rdegO[n2] * (h[row] @ W2m); row = w, col = l
    const int n2 = blockIdx.x * 4 + w;
    if (n2 < N) {
        const float* hr = h[w];
        float a = 0.0f;
        #pragma unroll 8
        for (int k = 0; k < 128; ++k) a += hr[k] * W2m[k * 64 + l];
        Ys[(size_t)n2 * 64 + l] = a * rdegO[n2];
    }
}

// out[n,:] = relu(rdegI[n]*sum Ys[s,:] + b1) @ w2 + b2  (wave reduction)
__global__ __launch_bounds__(256) void phase5(
    const float* __restrict__ Ys, const int* __restrict__ srcs,
    const int* __restrict__ row_ptr, const float* __restrict__ rdegI,
    const float* __restrict__ b1, const float* __restrict__ w2,
    const float* __restrict__ b2, float* __restrict__ out, int N)
{
    int n = (blockIdx.x * 256 + threadIdx.x) >> 6;
    int lane = threadIdx.x & 63;
    if (n >= N) return;
    int lo = row_ptr[n], hi = row_ptr[n + 1];
    float acc = 0.0f;
    for (int base = lo; base < hi; base += 64) {
        int cnt = min(hi - base, 64);
        int idx = (lane < cnt) ? srcs[base + lane] : 0;
        int j = 0;
        for (; j + 8 <= cnt; j += 8) {
            int s0 = __shfl(idx, j + 0), s1 = __shfl(idx, j + 1);
            int s2 = __shfl(idx, j + 2), s3 = __shfl(idx, j + 3);
            int s4 = __shfl(idx, j + 4), s5 = __shfl(idx, j + 5);
            int s6 = __shfl(idx, j + 6), s7 = __shfl(idx, j + 7);
            acc += Ys[(size_t)s0 * 64 + lane] + Ys[(size_t)s1 * 64 + lane]
                 + Ys[(size_t)s2 * 64 + lane] + Ys[(size_t)s3 * 64 + lane]
                 + Ys[(size_t)s4 * 64 + lane] + Ys[(size_t)s5 * 64 + lane]
                 + Ys[(size_t)s6 * 64 + lane] + Ys[(size_t)s7 * 64 + lane];
        }
        for (; j < cnt; ++j) {
            int s0 = __shfl(idx, j);
            acc += Ys[(size_t)s0 * 64 + lane];
        }
    }
    float z = acc * rdegI[n];
    float t = fmaxf(z + b1[lane], 0.0f);
    float p0 = t * w2[lane * 2 + 0];
    float p1 = t * w2[lane * 2 + 1];
    #pragma unroll
    for (int off = 32; off; off >>= 1) {
        p0 += __shfl_xor(p0, off);
        p1 += __shfl_xor(p1, off);
    }
    if (lane == 0) {
        out[(size_t)n * 2 + 0] = p0 + b2[0];
        out[(size_t)n * 2 + 1] = p1 + b2[1];
    }
}

extern "C" void kernel_launch(void* const* d_in, const int* in_sizes, int n_in,
                              void* d_out, int out_size, void* d_ws, size_t ws_size,
                              hipStream_t stream) {
    const float* feats = (const float*)d_in[0];
    const int*   src   = (const int*)d_in[1];
    const int*   dst   = (const int*)d_in[2];
    const float* W1_0  = (const float*)d_in[3];
    const float* W2_0  = (const float*)d_in[4];
    const float* g1W   = (const float*)d_in[5];
    const float* g1U   = (const float*)d_in[6];
    const float* g1b   = (const float*)d_in[7];
    const float* g2W   = (const float*)d_in[8];
    const float* g2U   = (const float*)d_in[9];
    const float* g2b   = (const float*)d_in[10];
    const float* mw1   = (const float*)d_in[11];
    const float* mb1   = (const float*)d_in[12];
    const float* mw2   = (const float*)d_in[13];
    const float* mb2   = (const float*)d_in[14];
    float* out = (float*)d_out;

    const int E = in_sizes[1];
    const int N = in_sizes[0] / (8 * 128);
    const int nbE = (E + 255) / 256;
    const int nbN = (N + 255) / 256;
    const int ngz = ((N + 1023) / 1024) * 8;

    // workspace layout
    float* ws    = (float*)d_ws;
    float* W1f   = ws;                        // 16384
    float* W2f   = W1f + 16384;               // 16384
    float* W2m   = W2f + 16384;               // 8192
    float* AT    = W2m + 8192;                // 8*16384
    float* rdegO = AT + 8 * 16384;            // N
    float* rdegI = rdegO + N;                 // N
    int*   degO  = (int*)(rdegI + N);         // N  ┐
    int*   degI  = degO + N;                  // N  ├ contiguous, one memset
    int*   cursor= degI + N;                  // N  ┘
    int*   row_ptr = cursor + N;              // N+1
    int*   srcs  = row_ptr + N + 1;           // E
    float* Zs    = (float*)(srcs + E);        // N*128
    float* Ys    = Zs + (size_t)N * 128;      // N*64

    const float* x7 = feats + (size_t)7 * N * 128;

    hipMemsetAsync(degO, 0, sizeof(int) * 3 * (size_t)N, stream);

    phase1<<<32 + nbE, 256, 0, stream>>>(src, dst, degO, degI, E,
                                         g1W, g1U, g2W, g2U, AT);

    phase2<<<129 + nbN, 256, 0, stream>>>(W1_0, W2_0, AT, g1b, g2b, W1f, W2f,
                                          degO, degI, rdegO, rdegI, row_ptr, N);

    phase3<<<nbE + ngz + 32, 256, 0, stream>>>(
        src, dst, row_ptr, cursor, srcs, E, nbE,
        x7, W1f, rdegO, Zs, N, ngz, W2f, mw1, W2m);

    phase4<<<(N + 3) / 4, 256, 0, stream>>>(Zs, srcs, row_ptr, rdegI, rdegO,
                                            W2m, Ys, N);

    phase5<<<(N + 3) / 4, 256, 0, stream>>>(Ys, srcs, row_ptr, rdegI,
                                            mb1, mw2, mb2, out, N);
}